// Round 8
// baseline (428.302 us; speedup 1.0000x reference)
//
#include <hip/hip_runtime.h>

// KacLayer: out[512][4096] = x @ W^T + b  +  Kac2( vec * Kac1( x ) )
//
//  kfused: blocks 0..11: per-8192-step window scheduler — fused
//          election+placement round loop (round-stamped atomicMin keys;
//          __syncthreads_count exit; per-(mc,wave) rank counters; (min,+)
//          capacity scan; winners scatter records straight to global, region
//          prefilled with identity-pad records). Invariant: column-sharing
//          steps are >=3 chunks apart => any 3 consecutive chunks are
//          column-disjoint. Bit-exact reorder of commuting Givens rotations.
//          blocks 12..1163: fp32->bf16 convert of W and X into d_ws.
//  kgemm_bf: bf16 MFMA GEMM from pre-converted W/X, 128x128 tile, BK=128,
//          XOR-swizzled LDS, Ksplit=2 (partial buffer in d_ws).
//  kwalk : 1 wave / 2 rows (float2-interleaved LDS), 3-stage pipeline
//          (records loaded +4, gathered +2, scattered at 0); epilogue adds
//          split-K partial + walked rows into out.

#define DIM    4096
#define ROWS   512
#define NSTEPS 49152
#define WSTEPS 8192
#define NW2    (NSTEPS / WSTEPS)   // 6 windows per walk
#define NSLOT  (2 * NW2)           // 12 slots
#define MAXCH  254
#define MAXCHP 256
#define NSG    16                  // rank subgroups (per wave, 1024 thr)
#define CHUNK  128
#define SLOT   (MAXCHP * CHUNK)    // 32768 records per slot
#define MAXR   64
#define GD     3                   // min chunk separation for dependent steps
#define PADI   4096
#define PADJ   4097
#define KT     1024                // scheduler threads
#define SPT    (WSTEPS / KT)       // 8 steps per thread
#define NCVW   1024                // W-convert blocks
#define NCVX   128                 // X-convert blocks

typedef short  short8 __attribute__((ext_vector_type(8)));
typedef __bf16 bf16x8 __attribute__((ext_vector_type(8)));
typedef float  f32x4  __attribute__((ext_vector_type(4)));

__device__ inline short f2bf(float f) {
    unsigned u = __builtin_bit_cast(unsigned, f);
    u += 0x7FFFu + ((u >> 16) & 1u);
    return (short)(u >> 16);
}
__device__ inline short8 pack8(float4 a, float4 b) {
    short8 r;
    r[0] = f2bf(a.x); r[1] = f2bf(a.y); r[2] = f2bf(a.z); r[3] = f2bf(a.w);
    r[4] = f2bf(b.x); r[5] = f2bf(b.y); r[6] = f2bf(b.z); r[7] = f2bf(b.w);
    return r;
}
__device__ inline float bitf(unsigned u) { return __builtin_bit_cast(float, u); }
__device__ inline float2 ldrw(const float2* rw, int boff) {
    return *(const float2*)((const char*)rw + boff);
}
__device__ inline void strw(float2* rw, int boff, float2 v) {
    *(float2*)((char*)rw + boff) = v;
}

// ---------------------------------------------------------------------------
// 1) fused scheduler (blocks 0..NSLOT-1) + bf16 convert (blocks NSLOT..)
// ---------------------------------------------------------------------------
__global__ __launch_bounds__(KT) void kfused(
    const int* __restrict__ i1, const int* __restrict__ j1,
    const float* __restrict__ c1, const float* __restrict__ s1,
    const int* __restrict__ i2, const int* __restrict__ j2,
    const float* __restrict__ c2, const float* __restrict__ s2,
    uint4* __restrict__ recs, int* __restrict__ cnts,
    int doconv, const float* __restrict__ W, const float* __restrict__ X,
    short* __restrict__ wb, short* __restrict__ xb) {

    // ---------------- convert path ----------------
    if (blockIdx.x >= NSLOT) {
        if (!doconv) return;
        const int cb = blockIdx.x - NSLOT;
        const float* src; short* dst; size_t base;
        if (cb < NCVW) { src = W; dst = wb; base = (size_t)cb * 16384; }
        else           { src = X; dst = xb; base = (size_t)(cb - NCVW) * 16384; }
        const size_t o = base + (size_t)threadIdx.x * 16;
        const float4* s4 = (const float4*)(src + o);
        const float4 a0 = s4[0], a1 = s4[1], a2 = s4[2], a3 = s4[3];
        *(short8*)(dst + o)     = pack8(a0, a1);
        *(short8*)(dst + o + 8) = pack8(a2, a3);
        return;
    }

    // ---------------- scheduler path ----------------
    __shared__ unsigned tbl[DIM];              // election keys (16 KB)
    __shared__ short    cchunk[DIM];           // last chunk per column (8 KB)
    __shared__ int want2[MAXCHP * NSG];        // rank counters / bases (16 KB)
    __shared__ int gsum[MAXCHP], cumpl[MAXCHP], fillb[MAXCHP], fillc[MAXCHP];
    __shared__ int maxcsh;

    const int b    = blockIdx.x;               // 0..11
    const int walk = b / NW2;
    const int w    = b % NW2;
    const int t    = threadIdx.x;
    const int gb   = w * WSTEPS;

    const int*   I = walk ? i2 : i1;
    const int*   J = walk ? j2 : j1;
    const float* C = walk ? c2 : c1;
    const float* S = walk ? s2 : s1;

    uint4* slotp = recs + (size_t)b * SLOT;

    // prefill the whole slot region with identity-pad records (coalesced)
    {
        const uint4 padrec = { (unsigned)(PADI * 8), 0x3F800000u, 0u, (unsigned)(PADJ * 8) };
        for (int k = t; k < SLOT; k += KT) slotp[k] = padrec;
    }

    unsigned short li[SPT], lj[SPT];
    signed char    myr[SPT];
    unsigned short mcst[SPT], grk[SPT];
#pragma unroll
    for (int q = 0; q < SPT; ++q) {
        const int s = q * KT + t;
        li[q] = (unsigned short)I[gb + s];
        lj[q] = (unsigned short)J[gb + s];
        myr[q] = -1;
    }
    for (int k = t; k < DIM; k += KT) { tbl[k] = 0xFFFFFFFFu; cchunk[k] = (short)(-GD); }
    if (t < MAXCHP) fillc[t] = 0;
    if (t == 0) maxcsh = 0;
    __syncthreads();

    unsigned pmask = (1u << SPT) - 1u;
    const int sg = t >> 6;                     // wave id 0..15

    for (int rr = 0; rr < MAXR; ++rr) {
        // P1: reset rank counters; pending steps stamp their columns
#pragma unroll
        for (int q = 0; q < 4; ++q) want2[t * 4 + q] = 0;
        const unsigned rk = (unsigned)(MAXR - 1 - rr) << 13;
#pragma unroll
        for (int q = 0; q < SPT; ++q)
            if (pmask & (1u << q)) {
                const unsigned key = rk | (unsigned)(q * KT + t);
                atomicMin(&tbl[li[q]], key);
                atomicMin(&tbl[lj[q]], key);
            }
        __syncthreads();                       // B1

        // P2: win check, compute min chunk, take rank within (mc, wave)
#pragma unroll
        for (int q = 0; q < SPT; ++q)
            if (pmask & (1u << q)) {
                const unsigned key = rk | (unsigned)(q * KT + t);
                if (tbl[li[q]] == key && tbl[lj[q]] == key) {
                    int a = (int)cchunk[li[q]], c = (int)cchunk[lj[q]];
                    int mc = ((a > c) ? a : c) + GD;
                    mc = (mc < 0) ? 0 : ((mc > MAXCH - 1) ? MAXCH - 1 : mc);
                    mcst[q] = (unsigned short)mc;
                    grk[q]  = (unsigned short)atomicAdd(&want2[mc * NSG + sg], 1);
                    myr[q]  = (signed char)rr;
                    pmask  &= ~(1u << q);
                }
            }
        const int np = __syncthreads_count(pmask != 0);   // B2

        // P3: one wave — per-mc subgroup prefixes, gsum, capacity (min,+) scan
        if (t < 64) {
            const int l = t;
            int inc[4], av[4], wq[4];
            int run = 0;
#pragma unroll
            for (int q = 0; q < 4; ++q) {
                const int mc = 4 * l + q;
                int ssum = 0;
                for (int g = 0; g < NSG; ++g) {
                    const int v = want2[mc * NSG + g];
                    want2[mc * NSG + g] = ssum;            // base within mc
                    ssum += v;
                }
                wq[q] = ssum;
                run  += ssum;
                inc[q] = run;
                av[q]  = (mc < MAXCH) ? (CHUNK - fillc[mc]) : 0;
            }
            int tot = run;
            for (int off = 1; off < 64; off <<= 1) {
                const int v = __shfl_up(tot, off);
                if (l >= off) tot += v;
            }
            const int basex = tot - run;
#pragma unroll
            for (int q = 0; q < 4; ++q) {
                gsum[4 * l + q] = basex + inc[q] - wq[q];
                inc[q] += basex;
            }
            int Iv = 1 << 29, Av = 0;                      // compose f(x)=min(I,A+x)
#pragma unroll
            for (int q = 0; q < 4; ++q) {
                const int cand = av[q] + Iv;
                Iv = (inc[q] < cand) ? inc[q] : cand;
                Av += av[q];
            }
            for (int off = 1; off < 64; off <<= 1) {
                const int Ip = __shfl_up(Iv, off), Ap = __shfl_up(Av, off);
                if (l >= off) {
                    const int cand = Av + Ip;
                    Iv = (Iv < cand) ? Iv : cand;
                    Av += Ap;
                }
            }
            const int Ie = __shfl_up(Iv, 1), Ae = __shfl_up(Av, 1);
            int placed = (l == 0) ? 0 : ((Ie < Ae) ? Ie : Ae);
#pragma unroll
            for (int q = 0; q < 4; ++q) {
                const int ch = 4 * l + q;
                const int cand = av[q] + placed;
                const int pnew = (inc[q] < cand) ? inc[q] : cand;
                const int take = pnew - placed;
                fillb[ch] = (ch < MAXCH) ? fillc[ch] : CHUNK;
                if (ch < MAXCH) fillc[ch] += take;
                cumpl[ch] = pnew;
                placed = pnew;
            }
        }
        __syncthreads();                       // B3

        // P4: winners place + scatter record + update column frontier
#pragma unroll
        for (int q = 0; q < SPT; ++q)
            if ((int)myr[q] == rr) {
                const int mc   = (int)mcst[q];
                const int fifo = gsum[mc] + want2[mc * NSG + sg] + (int)grk[q];
                int lo = 0, hi = MAXCHP - 1;
                while (lo < hi) {
                    const int mid = (lo + hi) >> 1;
                    if (cumpl[mid] > fifo) hi = mid; else lo = mid + 1;
                }
                const int ch   = lo;
                const int base = ch ? cumpl[ch - 1] : 0;
                const int p    = ch * CHUNK + fillb[ch] + (fifo - base);
                if (p < SLOT) {
                    const int g = gb + (q * KT + t);
                    uint4 r;
                    r.x = (unsigned)((int)li[q] * 8);
                    r.y = __builtin_bit_cast(unsigned, C[g]);
                    r.z = __builtin_bit_cast(unsigned, S[g]);
                    r.w = (unsigned)((int)lj[q] * 8);
                    slotp[p] = r;
                }
                cchunk[li[q]] = (short)ch;     // cols exclusive this round
                cchunk[lj[q]] = (short)ch;
            }
        __syncthreads();                       // B4
        if (np == 0) break;
    }

    // final: slot length = last used chunk + 2 trailing pad chunks
    if (t < MAXCHP && fillc[t] > 0) atomicMax(&maxcsh, t);
    __syncthreads();
    if (t == 0) {
        int mx = maxcsh; if (mx > MAXCH - 1) mx = MAXCH - 1;
        cnts[b] = (mx + 3) * CHUNK;
    }
}

// ---------------------------------------------------------------------------
// 2a) bf16 GEMM from pre-converted inputs: 128x128 tile, BK=128, Ksplit=2
// ---------------------------------------------------------------------------
__global__ __launch_bounds__(256) void kgemm_bf(const short* __restrict__ Xb, const short* __restrict__ Wb,
                                                const float* __restrict__ bias, float* __restrict__ out,
                                                float* __restrict__ parts) {
    __shared__ short As[128 * 128];
    __shared__ short Bs[128 * 128];
    const int bid  = blockIdx.x;
    const int ks   = bid & 1;
    const int tile = bid >> 1;                 // 0..127
    const int bm   = (tile >> 5) * 128;
    const int bn   = (tile & 31) * 128;
    const int tid  = threadIdx.x;
    const int lane = tid & 63;
    const int wv   = tid >> 6;
    const int wr   = (wv >> 1) * 64;
    const int wc   = (wv & 1) * 64;
    const int fr   = lane & 15;
    const int ke   = (lane >> 4) * 8;

    f32x4 acc[4][4];
#pragma unroll
    for (int m = 0; m < 4; ++m)
#pragma unroll
        for (int n = 0; n < 4; ++n) acc[m][n] = (f32x4){0.f, 0.f, 0.f, 0.f};

    const int tr2 = tid >> 1;                  // staging row 0..127
    const int hh  = tid & 1;                   // 64-elem half
    const int wm  = tr2 & 7;                   // swizzle mask
    const short* gxa = Xb + (size_t)(bm + tr2) * DIM + hh * 64;
    const short* gwb = Wb + (size_t)(bn + tr2) * DIM + hh * 64;

    for (int kt = 0; kt < 16; ++kt) {
        const int k0 = ks * 2048 + kt * 128;
        short8 ar[8], br[8];
#pragma unroll
        for (int q = 0; q < 8; ++q) ar[q] = *(const short8*)(gxa + k0 + q * 8);
#pragma unroll
        for (int q = 0; q < 8; ++q) br[q] = *(const short8*)(gwb + k0 + q * 8);
        __syncthreads();                       // previous tile's reads done
#pragma unroll
        for (int q = 0; q < 8; ++q) {
            const int sl = (hh * 8 + q) ^ wm;  // XOR-swizzled 16B slot
            *(short8*)&As[tr2 * 128 + sl * 8] = ar[q];
            *(short8*)&Bs[tr2 * 128 + sl * 8] = br[q];
        }
        __syncthreads();
#pragma unroll
        for (int kk = 0; kk < 128; kk += 32) {
            const int sbase = (kk + ke) >> 3;
            short8 af[4], bf[4];
#pragma unroll
            for (int m = 0; m < 4; ++m) {
                const int R = wr + m * 16 + fr;
                af[m] = *(const short8*)&As[R * 128 + ((sbase ^ (R & 7)) << 3)];
            }
#pragma unroll
            for (int n = 0; n < 4; ++n) {
                const int R = wc + n * 16 + fr;
                bf[n] = *(const short8*)&Bs[R * 128 + ((sbase ^ (R & 7)) << 3)];
            }
#pragma unroll
            for (int m = 0; m < 4; ++m)
#pragma unroll
                for (int n = 0; n < 4; ++n)
                    acc[m][n] = __builtin_amdgcn_mfma_f32_16x16x32_bf16(
                        __builtin_bit_cast(bf16x8, af[m]),
                        __builtin_bit_cast(bf16x8, bf[n]),
                        acc[m][n], 0, 0, 0);
        }
    }
    float* dst = ks ? parts : out;
#pragma unroll
    for (int n = 0; n < 4; ++n) {
        const int col = bn + wc + n * 16 + fr;
        const float bv = ks ? 0.f : bias[col];
#pragma unroll
        for (int m = 0; m < 4; ++m) {
            const int rbase = bm + wr + m * 16 + (lane >> 4) * 4;
#pragma unroll
            for (int r = 0; r < 4; ++r)
                dst[(size_t)(rbase + r) * DIM + col] = acc[m][n][r] + bv;
        }
    }
}

// ---------------------------------------------------------------------------
// 2b) fallback GEMM: fp32 staging, BM=64 BN=128, full K, 256 thr
// ---------------------------------------------------------------------------
#define LDT 72
__global__ __launch_bounds__(256) void kgemm_small(const float* __restrict__ X, const float* __restrict__ W,
                                                   const float* __restrict__ bias, float* __restrict__ out) {
    __shared__ short As[64 * LDT];
    __shared__ short Bs[128 * LDT];
    const int tid  = threadIdx.x;
    const int bn   = (blockIdx.x & 31) * 128;
    const int bm   = (blockIdx.x >> 5) * 64;
    const int lane = tid & 63;
    const int wv   = tid >> 6;
    const int wr   = (wv >> 1) * 32;
    const int wc   = (wv & 1) * 64;
    const int fr   = lane & 15;
    const int ke   = (lane >> 4) * 8;

    f32x4 acc[2][4];
#pragma unroll
    for (int m = 0; m < 2; ++m)
#pragma unroll
        for (int n = 0; n < 4; ++n) acc[m][n] = (f32x4){0.f, 0.f, 0.f, 0.f};

    const int tr = tid >> 2;
    const int tc = (tid & 3) << 4;

    for (int kt = 0; kt < DIM / 64; ++kt) {
        const int k0 = kt * 64;
        float4 ra[4], rb[2][4];
        {
            const float4* ga = (const float4*)(X + (size_t)(bm + tr) * DIM + k0 + tc);
#pragma unroll
            for (int q = 0; q < 4; ++q) ra[q] = ga[q];
#pragma unroll
            for (int h = 0; h < 2; ++h) {
                const float4* gw = (const float4*)(W + (size_t)(bn + h * 64 + tr) * DIM + k0 + tc);
#pragma unroll
                for (int q = 0; q < 4; ++q) rb[h][q] = gw[q];
            }
        }
        __syncthreads();
        *(short8*)&As[tr * LDT + tc]     = pack8(ra[0], ra[1]);
        *(short8*)&As[tr * LDT + tc + 8] = pack8(ra[2], ra[3]);
#pragma unroll
        for (int h = 0; h < 2; ++h) {
            *(short8*)&Bs[(h * 64 + tr) * LDT + tc]     = pack8(rb[h][0], rb[h][1]);
            *(short8*)&Bs[(h * 64 + tr) * LDT + tc + 8] = pack8(rb[h][2], rb[h][3]);
        }
        __syncthreads();
#pragma unroll
        for (int kk = 0; kk < 64; kk += 32) {
            short8 af[2], bf[4];
#pragma unroll
            for (int m = 0; m < 2; ++m)
                af[m] = *(const short8*)&As[(wr + m * 16 + fr) * LDT + kk + ke];
#pragma unroll
            for (int n = 0; n < 4; ++n)
                bf[n] = *(const short8*)&Bs[(wc + n * 16 + fr) * LDT + kk + ke];
#pragma unroll
            for (int m = 0; m < 2; ++m)
#pragma unroll
                for (int n = 0; n < 4; ++n)
                    acc[m][n] = __builtin_amdgcn_mfma_f32_16x16x32_bf16(
                        __builtin_bit_cast(bf16x8, af[m]),
                        __builtin_bit_cast(bf16x8, bf[n]),
                        acc[m][n], 0, 0, 0);
        }
    }
#pragma unroll
    for (int n = 0; n < 4; ++n) {
        const int col = bn + wc + n * 16 + fr;
        const float bv = bias[col];
#pragma unroll
        for (int m = 0; m < 2; ++m) {
            const int rbase = bm + wr + m * 16 + (lane >> 4) * 4;
#pragma unroll
            for (int r = 0; r < 4; ++r)
                out[(size_t)(rbase + r) * DIM + col] = acc[m][n][r] + bv;
        }
    }
}

// ---------------------------------------------------------------------------
// 3) walk kernel: 1 wave / 2 rows, 3-stage pipeline; adds split-K partial
// ---------------------------------------------------------------------------
__global__ __launch_bounds__(64) void kwalk(const float* __restrict__ X, const float* __restrict__ vec,
                                            const uint4* __restrict__ recs, const int* __restrict__ cnts,
                                            const float* __restrict__ parts, int nparts,
                                            float* __restrict__ out) {
    __shared__ float2 rw[DIM + 2];
    const int pr   = blockIdx.x;
    const int lane = threadIdx.x;
    const int rA   = pr * 2, rB = pr * 2 + 1;

    {
        const float4* xa = (const float4*)(X + (size_t)rA * DIM);
        const float4* xb = (const float4*)(X + (size_t)rB * DIM);
        for (int c4 = lane; c4 < DIM / 4; c4 += 64) {
            const float4 a = xa[c4], b = xb[c4];
            rw[c4 * 4 + 0] = make_float2(a.x, b.x);
            rw[c4 * 4 + 1] = make_float2(a.y, b.y);
            rw[c4 * 4 + 2] = make_float2(a.z, b.z);
            rw[c4 * 4 + 3] = make_float2(a.w, b.w);
        }
        if (lane < 2) rw[DIM + lane] = make_float2(0.f, 0.f);
    }

    const int cnreg = cnts[lane < NSLOT ? lane : 0];

    for (int slot = 0; slot < NSLOT; ++slot) {
        if (slot == NW2) {      // between walks: yp = vec * yp
            const float4* v4 = (const float4*)vec;
            for (int c4 = lane; c4 < DIM / 4; c4 += 64) {
                const float4 v = v4[c4];
#pragma unroll
                for (int q = 0; q < 4; ++q) {
                    float2 tv = rw[c4 * 4 + q];
                    const float sc = (q == 0) ? v.x : (q == 1) ? v.y : (q == 2) ? v.z : v.w;
                    tv.x *= sc; tv.y *= sc;
                    rw[c4 * 4 + q] = tv;
                }
            }
        }
        const int nit = __shfl(cnreg, slot) >> 7;
        const uint4* base = recs + (size_t)slot * SLOT;

        uint4 rd0A = base[2 * 128 + lane], rd0B = base[2 * 128 + 64 + lane];
        uint4 rd1A = base[3 * 128 + lane], rd1B = base[3 * 128 + 64 + lane];
        uint4 c0A  = base[lane],           c0B  = base[64 + lane];
        uint4 c1A  = base[128 + lane],     c1B  = base[192 + lane];

        int   i0a = (int)c0A.x, j0a = (int)c0A.w;   // byte offsets
        int   i0b = (int)c0B.x, j0b = (int)c0B.w;
        float cc0a = bitf(c0A.y), ss0a = bitf(c0A.z);
        float cc0b = bitf(c0B.y), ss0b = bitf(c0B.z);
        float2 g0ai = ldrw(rw, i0a), g0aj = ldrw(rw, j0a);
        float2 g0bi = ldrw(rw, i0b), g0bj = ldrw(rw, j0b);

        int   i1a = (int)c1A.x, j1a = (int)c1A.w;
        int   i1b = (int)c1B.x, j1b = (int)c1B.w;
        float cc1a = bitf(c1A.y), ss1a = bitf(c1A.z);
        float cc1b = bitf(c1B.y), ss1b = bitf(c1B.z);
        float2 g1ai = ldrw(rw, i1a), g1aj = ldrw(rw, j1a);
        float2 g1bi = ldrw(rw, i1b), g1bj = ldrw(rw, j1b);

#pragma unroll 4
        for (int k = 0; k < nit; ++k) {
            // stage L: load records for chunk k+4 (clamped -> trailing pads)
            const int kc = (k + 4 < nit) ? (k + 4) : (nit - 1);
            const uint4 mA = base[(size_t)kc * 128 + lane];
            const uint4 mB = base[(size_t)kc * 128 + 64 + lane];

            // stage G: gather chunk k+2 (any 3 consecutive chunks disjoint)
            const int   i2a = (int)rd0A.x, j2a = (int)rd0A.w;
            const int   i2b = (int)rd0B.x, j2b = (int)rd0B.w;
            const float cc2a = bitf(rd0A.y), ss2a = bitf(rd0A.z);
            const float cc2b = bitf(rd0B.y), ss2b = bitf(rd0B.z);
            const float2 g2ai = ldrw(rw, i2a), g2aj = ldrw(rw, j2a);
            const float2 g2bi = ldrw(rw, i2b), g2bj = ldrw(rw, j2b);

            // stage C: rotate + scatter chunk k
            float2 wia, wja, wib, wjb;
            wia.x = fmaf(cc0a, g0ai.x,  ss0a * g0aj.x);
            wia.y = fmaf(cc0a, g0ai.y,  ss0a * g0aj.y);
            wja.x = fmaf(cc0a, g0aj.x, -ss0a * g0ai.x);
            wja.y = fmaf(cc0a, g0aj.y, -ss0a * g0ai.y);
            wib.x = fmaf(cc0b, g0bi.x,  ss0b * g0bj.x);
            wib.y = fmaf(cc0b, g0bi.y,  ss0b * g0bj.y);
            wjb.x = fmaf(cc0b, g0bj.x, -ss0b * g0bi.x);
            wjb.y = fmaf(cc0b, g0bj.y, -ss0b * g0bi.y);
            strw(rw, i0a, wia); strw(rw, j0a, wja);
            strw(rw, i0b, wib); strw(rw, j0b, wjb);

            i0a = i1a; j0a = j1a; cc0a = cc1a; ss0a = ss1a; g0ai = g1ai; g0aj = g1aj;
            i0b = i1b; j0b = j1b; cc0b = cc1b; ss0b = ss1b; g0bi = g1bi; g0bj = g1bj;
            i1a = i2a; j1a = j2a; cc1a = cc2a; ss1a = ss2a; g1ai = g2ai; g1aj = g2aj;
            i1b = i2b; j1b = j2b; cc1b = cc2b; ss1b = ss2b; g1bi = g2bi; g1bj = g2bj;
            rd0A = rd1A; rd0B = rd1B; rd1A = mA; rd1B = mB;
        }
    }

    float4* oa = (float4*)(out + (size_t)rA * DIM);
    float4* ob = (float4*)(out + (size_t)rB * DIM);
    const float4* qa = (const float4*)parts + (size_t)rA * (DIM / 4);
    const float4* qb = (const float4*)parts + (size_t)rB * (DIM / 4);
    for (int c4 = lane; c4 < DIM / 4; c4 += 64) {
        const float2 p0 = rw[c4 * 4 + 0], p1 = rw[c4 * 4 + 1];
        const float2 p2 = rw[c4 * 4 + 2], p3 = rw[c4 * 4 + 3];
        float4 ta = oa[c4], tb = ob[c4];
        if (nparts == 1) {
            const float4 a0 = qa[c4], b0 = qb[c4];
            ta.x += a0.x; ta.y += a0.y; ta.z += a0.z; ta.w += a0.w;
            tb.x += b0.x; tb.y += b0.y; tb.z += b0.z; tb.w += b0.w;
        }
        ta.x += p0.x; ta.y += p1.x; ta.z += p2.x; ta.w += p3.x;
        tb.x += p0.y; tb.y += p1.y; tb.z += p2.y; tb.w += p3.y;
        oa[c4] = ta; ob[c4] = tb;
    }
}

// ---------------------------------------------------------------------------
extern "C" void kernel_launch(void* const* d_in, const int* in_sizes, int n_in,
                              void* d_out, int out_size, void* d_ws, size_t ws_size,
                              hipStream_t stream) {
    const float* X    = (const float*)d_in[0];
    const float* W    = (const float*)d_in[1];
    const float* bias = (const float*)d_in[2];
    const float* vec  = (const float*)d_in[3];
    const int*   i1   = (const int*)d_in[4];
    const int*   j1   = (const int*)d_in[5];
    const float* c1   = (const float*)d_in[6];
    const float* s1   = (const float*)d_in[7];
    const int*   i2   = (const int*)d_in[8];
    const int*   j2   = (const int*)d_in[9];
    const float* c2   = (const float*)d_in[10];
    const float* s2   = (const float*)d_in[11];
    float* out = (float*)d_out;

    const size_t recs_bytes = (size_t)NSLOT * SLOT * 16;         // 6.29 MiB
    const size_t off_parts  = recs_bytes + 4096;
    const size_t off_wb     = off_parts + (size_t)ROWS * DIM * 4;    // +8 MiB
    const size_t off_xb     = off_wb + (size_t)DIM * DIM * 2;        // +32 MiB
    const size_t need       = off_xb + (size_t)ROWS * DIM * 2;       // +4 MiB

    uint4* recs  = (uint4*)d_ws;
    int*   cnts  = (int*)((char*)d_ws + recs_bytes);
    float* parts = (float*)((char*)d_ws + off_parts);
    short* wbuf  = (short*)((char*)d_ws + off_wb);
    short* xbuf  = (short*)((char*)d_ws + off_xb);
    const bool bf = (ws_size >= need);

    hipLaunchKernelGGL(kfused, dim3(NSLOT + (bf ? (NCVW + NCVX) : 0)), dim3(KT), 0, stream,
                       i1, j1, c1, s1, i2, j2, c2, s2, recs, cnts,
                       bf ? 1 : 0, W, X, wbuf, xbuf);
    if (bf)
        hipLaunchKernelGGL(kgemm_bf, dim3(256), dim3(256), 0, stream, xbuf, wbuf, bias, out, parts);
    else
        hipLaunchKernelGGL(kgemm_small, dim3(256), dim3(256), 0, stream, X, W, bias, out);
    hipLaunchKernelGGL(kwalk, dim3(ROWS / 2), dim3(64), 0, stream,
                       X, vec, recs, cnts, parts, bf ? 1 : 0, out);
}

// Round 9
// 399.881 us; speedup vs baseline: 1.0711x; 1.0711x over previous
//
#include <hip/hip_runtime.h>

// KacLayer: out[512][4096] = x @ W^T + b  +  Kac2( vec * Kac1( x ) )
//
//  kfused: blocks 0..11: per-8192-step window scheduler — fused
//          election+placement round loop. ALL per-step state lives in LDS
//          (spair/mcrk) so the 1024-thread 64-VGPR cap causes no scratch
//          spills (R8's 260us failure mode). Winners scatter records straight
//          to global (region prefilled with identity pads). Invariant:
//          column-sharing steps >=3 chunks apart => any 3 consecutive chunks
//          column-disjoint. Bit-exact reorder of commuting Givens rotations.
//          blocks 12..1163: fp32->bf16 convert of W and X into d_ws.
//  kgemm_bf: bf16 MFMA GEMM from pre-converted W/X, 128x128 tile, BK=128,
//          XOR-swizzled LDS, Ksplit=2 (partial buffer in d_ws).
//  kwalk : 1 wave / 2 rows (float2-interleaved LDS), 3-stage pipeline
//          (records loaded +4, gathered +2, scattered at 0); epilogue adds
//          split-K partial + walked rows into out.

#define DIM    4096
#define ROWS   512
#define NSTEPS 49152
#define WSTEPS 8192
#define NW2    (NSTEPS / WSTEPS)   // 6 windows per walk
#define NSLOT  (2 * NW2)           // 12 slots
#define MAXCH  254
#define MAXCHP 256
#define NSG    16                  // rank subgroups (per wave, 1024 thr)
#define CHUNK  128
#define SLOT   (MAXCHP * CHUNK)    // 32768 records per slot
#define MAXR   96
#define GD     3                   // min chunk separation for dependent steps
#define PADI   4096
#define PADJ   4097
#define KT     1024                // scheduler threads
#define SPT    (WSTEPS / KT)       // 8 steps per thread
#define NCVW   1024                // W-convert blocks
#define NCVX   128                 // X-convert blocks

typedef short  short8 __attribute__((ext_vector_type(8)));
typedef __bf16 bf16x8 __attribute__((ext_vector_type(8)));
typedef float  f32x4  __attribute__((ext_vector_type(4)));

__device__ inline short f2bf(float f) {
    unsigned u = __builtin_bit_cast(unsigned, f);
    u += 0x7FFFu + ((u >> 16) & 1u);
    return (short)(u >> 16);
}
__device__ inline short8 pack8(float4 a, float4 b) {
    short8 r;
    r[0] = f2bf(a.x); r[1] = f2bf(a.y); r[2] = f2bf(a.z); r[3] = f2bf(a.w);
    r[4] = f2bf(b.x); r[5] = f2bf(b.y); r[6] = f2bf(b.z); r[7] = f2bf(b.w);
    return r;
}
__device__ inline float bitf(unsigned u) { return __builtin_bit_cast(float, u); }
__device__ inline float2 ldrw(const float2* rw, int boff) {
    return *(const float2*)((const char*)rw + boff);
}
__device__ inline void strw(float2* rw, int boff, float2 v) {
    *(float2*)((char*)rw + boff) = v;
}

// ---------------------------------------------------------------------------
// 1) fused scheduler (blocks 0..NSLOT-1) + bf16 convert (blocks NSLOT..)
// ---------------------------------------------------------------------------
__global__ __launch_bounds__(KT) void kfused(
    const int* __restrict__ i1, const int* __restrict__ j1,
    const float* __restrict__ c1, const float* __restrict__ s1,
    const int* __restrict__ i2, const int* __restrict__ j2,
    const float* __restrict__ c2, const float* __restrict__ s2,
    uint4* __restrict__ recs, int* __restrict__ cnts,
    int doconv, const float* __restrict__ W, const float* __restrict__ X,
    short* __restrict__ wb, short* __restrict__ xb) {

    // ---------------- convert path ----------------
    if (blockIdx.x >= NSLOT) {
        if (!doconv) return;
        const int cb = blockIdx.x - NSLOT;
        const float* src; short* dst; size_t base;
        if (cb < NCVW) { src = W; dst = wb; base = (size_t)cb * 16384; }
        else           { src = X; dst = xb; base = (size_t)(cb - NCVW) * 16384; }
        const size_t o = base + (size_t)threadIdx.x * 16;
        const float4* s4 = (const float4*)(src + o);
        const float4 a0 = s4[0], a1 = s4[1], a2 = s4[2], a3 = s4[3];
        *(short8*)(dst + o)     = pack8(a0, a1);
        *(short8*)(dst + o + 8) = pack8(a2, a3);
        return;
    }

    // ---------------- scheduler path (all per-step state in LDS) ----------
    __shared__ unsigned tbl[DIM];              // election keys   (16 KB)
    __shared__ unsigned spair[WSTEPS];         // li | lj<<16     (32 KB)
    __shared__ unsigned mcrk[WSTEPS];          // mc | rank<<16   (32 KB)
    __shared__ short    cchunk[DIM];           // col frontier     (8 KB)
    __shared__ int want2[MAXCHP * NSG];        // rank counters   (16 KB)
    __shared__ int gsum[MAXCHP], cumpl[MAXCHP], fillb[MAXCHP], fillc[MAXCHP];
    __shared__ int maxcsh;

    const int b    = blockIdx.x;               // 0..11
    const int walk = b / NW2;
    const int w    = b % NW2;
    const int t    = threadIdx.x;
    const int gb   = w * WSTEPS;

    const int*   I = walk ? i2 : i1;
    const int*   J = walk ? j2 : j1;
    const float* C = walk ? c2 : c1;
    const float* S = walk ? s2 : s1;

    uint4* slotp = recs + (size_t)b * SLOT;

    // prefill slot region with identity-pad records (coalesced)
    {
        const uint4 padrec = { (unsigned)(PADI * 8), 0x3F800000u, 0u, (unsigned)(PADJ * 8) };
        for (int k = t; k < SLOT; k += KT) slotp[k] = padrec;
    }
    for (int s = t; s < WSTEPS; s += KT)
        spair[s] = (unsigned)I[gb + s] | ((unsigned)J[gb + s] << 16);
    for (int k = t; k < DIM; k += KT) { tbl[k] = 0xFFFFFFFFu; cchunk[k] = (short)(-GD); }
    if (t < MAXCHP) fillc[t] = 0;
    if (t == 0) maxcsh = 0;
    __syncthreads();

    unsigned pmask = (1u << SPT) - 1u;
    const int sg = t >> 6;                     // wave id 0..15

    for (int rr = 0; rr < MAXR; ++rr) {
        // P1: reset rank counters; pending steps stamp their columns
#pragma unroll
        for (int q = 0; q < 4; ++q) want2[t * 4 + q] = 0;
        const unsigned rk = (unsigned)(MAXR - 1 - rr) << 13;
#pragma unroll
        for (int q = 0; q < SPT; ++q)
            if (pmask & (1u << q)) {
                const int s = q * KT + t;
                const unsigned sp = spair[s];
                const unsigned key = rk | (unsigned)s;
                atomicMin(&tbl[sp & 0xFFFFu], key);
                atomicMin(&tbl[sp >> 16], key);
            }
        __syncthreads();                       // B1

        // P2: win check, compute min chunk, take rank within (mc, wave)
        unsigned wmask = 0;
#pragma unroll
        for (int q = 0; q < SPT; ++q)
            if (pmask & (1u << q)) {
                const int s = q * KT + t;
                const unsigned sp = spair[s];
                const int li = (int)(sp & 0xFFFFu), lj = (int)(sp >> 16);
                const unsigned key = rk | (unsigned)s;
                if (tbl[li] == key && tbl[lj] == key) {
                    int a = (int)cchunk[li], c = (int)cchunk[lj];
                    int mc = ((a > c) ? a : c) + GD;
                    mc = (mc < 0) ? 0 : ((mc > MAXCH - 1) ? MAXCH - 1 : mc);
                    const int rank = atomicAdd(&want2[mc * NSG + sg], 1);
                    mcrk[s] = (unsigned)mc | ((unsigned)rank << 16);
                    wmask |= (1u << q);
                    pmask &= ~(1u << q);
                }
            }
        const int np = __syncthreads_count(pmask != 0);   // B2

        // P3: one wave — per-mc subgroup prefixes, gsum, capacity (min,+) scan
        if (t < 64) {
            const int l = t;
            int inc[4], av[4], wq[4];
            int run = 0;
#pragma unroll
            for (int q = 0; q < 4; ++q) {
                const int mc = 4 * l + q;
                int ssum = 0;
                for (int g = 0; g < NSG; ++g) {
                    const int v = want2[mc * NSG + g];
                    want2[mc * NSG + g] = ssum;            // base within mc
                    ssum += v;
                }
                wq[q] = ssum;
                run  += ssum;
                inc[q] = run;
                av[q]  = (mc < MAXCH) ? (CHUNK - fillc[mc]) : 0;
            }
            int tot = run;
            for (int off = 1; off < 64; off <<= 1) {
                const int v = __shfl_up(tot, off);
                if (l >= off) tot += v;
            }
            const int basex = tot - run;
#pragma unroll
            for (int q = 0; q < 4; ++q) {
                gsum[4 * l + q] = basex + inc[q] - wq[q];
                inc[q] += basex;
            }
            int Iv = 1 << 29, Av = 0;                      // compose f(x)=min(I,A+x)
#pragma unroll
            for (int q = 0; q < 4; ++q) {
                const int cand = av[q] + Iv;
                Iv = (inc[q] < cand) ? inc[q] : cand;
                Av += av[q];
            }
            for (int off = 1; off < 64; off <<= 1) {
                const int Ip = __shfl_up(Iv, off), Ap = __shfl_up(Av, off);
                if (l >= off) {
                    const int cand = Av + Ip;
                    Iv = (Iv < cand) ? Iv : cand;
                    Av += Ap;
                }
            }
            const int Ie = __shfl_up(Iv, 1), Ae = __shfl_up(Av, 1);
            int placed = (l == 0) ? 0 : ((Ie < Ae) ? Ie : Ae);
#pragma unroll
            for (int q = 0; q < 4; ++q) {
                const int ch = 4 * l + q;
                const int cand = av[q] + placed;
                const int pnew = (inc[q] < cand) ? inc[q] : cand;
                const int take = pnew - placed;
                fillb[ch] = (ch < MAXCH) ? fillc[ch] : CHUNK;
                if (ch < MAXCH) fillc[ch] += take;
                cumpl[ch] = pnew;
                placed = pnew;
            }
        }
        __syncthreads();                       // B3

        // P4: winners place + scatter record + update column frontier
#pragma unroll
        for (int q = 0; q < SPT; ++q)
            if (wmask & (1u << q)) {
                const int s = q * KT + t;
                const unsigned v = mcrk[s];
                const int mc = (int)(v & 0xFFFFu), rank = (int)(v >> 16);
                const int fifo = gsum[mc] + want2[mc * NSG + sg] + rank;
                int lo = 0, hi = MAXCHP - 1;
                while (lo < hi) {
                    const int mid = (lo + hi) >> 1;
                    if (cumpl[mid] > fifo) hi = mid; else lo = mid + 1;
                }
                const int ch   = lo;
                const int base = ch ? cumpl[ch - 1] : 0;
                const int p    = ch * CHUNK + fillb[ch] + (fifo - base);
                const unsigned sp = spair[s];
                const int li = (int)(sp & 0xFFFFu), lj = (int)(sp >> 16);
                if (p < SLOT) {
                    const int g = gb + s;
                    uint4 r;
                    r.x = (unsigned)(li * 8);
                    r.y = __builtin_bit_cast(unsigned, C[g]);
                    r.z = __builtin_bit_cast(unsigned, S[g]);
                    r.w = (unsigned)(lj * 8);
                    slotp[p] = r;
                }
                cchunk[li] = (short)ch;        // cols exclusive this round
                cchunk[lj] = (short)ch;
            }
        __syncthreads();                       // B4
        if (np == 0) break;
    }

    // final: slot length = last used chunk + 2 trailing pad chunks
    if (t < MAXCHP && fillc[t] > 0) atomicMax(&maxcsh, t);
    __syncthreads();
    if (t == 0) {
        int mx = maxcsh; if (mx > MAXCH - 1) mx = MAXCH - 1;
        cnts[b] = (mx + 3) * CHUNK;
    }
}

// ---------------------------------------------------------------------------
// 2a) bf16 GEMM from pre-converted inputs: 128x128 tile, BK=128, Ksplit=2
// ---------------------------------------------------------------------------
__global__ __launch_bounds__(256) void kgemm_bf(const short* __restrict__ Xb, const short* __restrict__ Wb,
                                                const float* __restrict__ bias, float* __restrict__ out,
                                                float* __restrict__ parts) {
    __shared__ short As[128 * 128];
    __shared__ short Bs[128 * 128];
    const int bid  = blockIdx.x;
    const int ks   = bid & 1;
    const int tile = bid >> 1;                 // 0..127
    const int bm   = (tile >> 5) * 128;
    const int bn   = (tile & 31) * 128;
    const int tid  = threadIdx.x;
    const int lane = tid & 63;
    const int wv   = tid >> 6;
    const int wr   = (wv >> 1) * 64;
    const int wc   = (wv & 1) * 64;
    const int fr   = lane & 15;
    const int ke   = (lane >> 4) * 8;

    f32x4 acc[4][4];
#pragma unroll
    for (int m = 0; m < 4; ++m)
#pragma unroll
        for (int n = 0; n < 4; ++n) acc[m][n] = (f32x4){0.f, 0.f, 0.f, 0.f};

    const int tr2 = tid >> 1;                  // staging row 0..127
    const int hh  = tid & 1;                   // 64-elem half
    const int wm  = tr2 & 7;                   // swizzle mask
    const short* gxa = Xb + (size_t)(bm + tr2) * DIM + hh * 64;
    const short* gwb = Wb + (size_t)(bn + tr2) * DIM + hh * 64;

    for (int kt = 0; kt < 16; ++kt) {
        const int k0 = ks * 2048 + kt * 128;
        short8 ar[8], br[8];
#pragma unroll
        for (int q = 0; q < 8; ++q) ar[q] = *(const short8*)(gxa + k0 + q * 8);
#pragma unroll
        for (int q = 0; q < 8; ++q) br[q] = *(const short8*)(gwb + k0 + q * 8);
        __syncthreads();                       // previous tile's reads done
#pragma unroll
        for (int q = 0; q < 8; ++q) {
            const int sl = (hh * 8 + q) ^ wm;  // XOR-swizzled 16B slot
            *(short8*)&As[tr2 * 128 + sl * 8] = ar[q];
            *(short8*)&Bs[tr2 * 128 + sl * 8] = br[q];
        }
        __syncthreads();
#pragma unroll
        for (int kk = 0; kk < 128; kk += 32) {
            const int sbase = (kk + ke) >> 3;
            short8 af[4], bf[4];
#pragma unroll
            for (int m = 0; m < 4; ++m) {
                const int R = wr + m * 16 + fr;
                af[m] = *(const short8*)&As[R * 128 + ((sbase ^ (R & 7)) << 3)];
            }
#pragma unroll
            for (int n = 0; n < 4; ++n) {
                const int R = wc + n * 16 + fr;
                bf[n] = *(const short8*)&Bs[R * 128 + ((sbase ^ (R & 7)) << 3)];
            }
#pragma unroll
            for (int m = 0; m < 4; ++m)
#pragma unroll
                for (int n = 0; n < 4; ++n)
                    acc[m][n] = __builtin_amdgcn_mfma_f32_16x16x32_bf16(
                        __builtin_bit_cast(bf16x8, af[m]),
                        __builtin_bit_cast(bf16x8, bf[n]),
                        acc[m][n], 0, 0, 0);
        }
    }
    float* dst = ks ? parts : out;
#pragma unroll
    for (int n = 0; n < 4; ++n) {
        const int col = bn + wc + n * 16 + fr;
        const float bv = ks ? 0.f : bias[col];
#pragma unroll
        for (int m = 0; m < 4; ++m) {
            const int rbase = bm + wr + m * 16 + (lane >> 4) * 4;
#pragma unroll
            for (int r = 0; r < 4; ++r)
                dst[(size_t)(rbase + r) * DIM + col] = acc[m][n][r] + bv;
        }
    }
}

// ---------------------------------------------------------------------------
// 2b) fallback GEMM: fp32 staging, BM=64 BN=128, full K, 256 thr
// ---------------------------------------------------------------------------
#define LDT 72
__global__ __launch_bounds__(256) void kgemm_small(const float* __restrict__ X, const float* __restrict__ W,
                                                   const float* __restrict__ bias, float* __restrict__ out) {
    __shared__ short As[64 * LDT];
    __shared__ short Bs[128 * LDT];
    const int tid  = threadIdx.x;
    const int bn   = (blockIdx.x & 31) * 128;
    const int bm   = (blockIdx.x >> 5) * 64;
    const int lane = tid & 63;
    const int wv   = tid >> 6;
    const int wr   = (wv >> 1) * 32;
    const int wc   = (wv & 1) * 64;
    const int fr   = lane & 15;
    const int ke   = (lane >> 4) * 8;

    f32x4 acc[2][4];
#pragma unroll
    for (int m = 0; m < 2; ++m)
#pragma unroll
        for (int n = 0; n < 4; ++n) acc[m][n] = (f32x4){0.f, 0.f, 0.f, 0.f};

    const int tr = tid >> 2;
    const int tc = (tid & 3) << 4;

    for (int kt = 0; kt < DIM / 64; ++kt) {
        const int k0 = kt * 64;
        float4 ra[4], rb[2][4];
        {
            const float4* ga = (const float4*)(X + (size_t)(bm + tr) * DIM + k0 + tc);
#pragma unroll
            for (int q = 0; q < 4; ++q) ra[q] = ga[q];
#pragma unroll
            for (int h = 0; h < 2; ++h) {
                const float4* gw = (const float4*)(W + (size_t)(bn + h * 64 + tr) * DIM + k0 + tc);
#pragma unroll
                for (int q = 0; q < 4; ++q) rb[h][q] = gw[q];
            }
        }
        __syncthreads();
        *(short8*)&As[tr * LDT + tc]     = pack8(ra[0], ra[1]);
        *(short8*)&As[tr * LDT + tc + 8] = pack8(ra[2], ra[3]);
#pragma unroll
        for (int h = 0; h < 2; ++h) {
            *(short8*)&Bs[(h * 64 + tr) * LDT + tc]     = pack8(rb[h][0], rb[h][1]);
            *(short8*)&Bs[(h * 64 + tr) * LDT + tc + 8] = pack8(rb[h][2], rb[h][3]);
        }
        __syncthreads();
#pragma unroll
        for (int kk = 0; kk < 64; kk += 32) {
            short8 af[2], bf[4];
#pragma unroll
            for (int m = 0; m < 2; ++m)
                af[m] = *(const short8*)&As[(wr + m * 16 + fr) * LDT + kk + ke];
#pragma unroll
            for (int n = 0; n < 4; ++n)
                bf[n] = *(const short8*)&Bs[(wc + n * 16 + fr) * LDT + kk + ke];
#pragma unroll
            for (int m = 0; m < 2; ++m)
#pragma unroll
                for (int n = 0; n < 4; ++n)
                    acc[m][n] = __builtin_amdgcn_mfma_f32_16x16x32_bf16(
                        __builtin_bit_cast(bf16x8, af[m]),
                        __builtin_bit_cast(bf16x8, bf[n]),
                        acc[m][n], 0, 0, 0);
        }
    }
#pragma unroll
    for (int n = 0; n < 4; ++n) {
        const int col = bn + wc + n * 16 + fr;
        const float bv = bias[col];
#pragma unroll
        for (int m = 0; m < 2; ++m) {
            const int rbase = bm + wr + m * 16 + (lane >> 4) * 4;
#pragma unroll
            for (int r = 0; r < 4; ++r)
                out[(size_t)(rbase + r) * DIM + col] = acc[m][n][r] + bv;
        }
    }
}

// ---------------------------------------------------------------------------
// 3) walk kernel: 1 wave / 2 rows, 3-stage pipeline; adds split-K partial
// ---------------------------------------------------------------------------
__global__ __launch_bounds__(64) void kwalk(const float* __restrict__ X, const float* __restrict__ vec,
                                            const uint4* __restrict__ recs, const int* __restrict__ cnts,
                                            const float* __restrict__ parts, int nparts,
                                            float* __restrict__ out) {
    __shared__ float2 rw[DIM + 2];
    const int pr   = blockIdx.x;
    const int lane = threadIdx.x;
    const int rA   = pr * 2, rB = pr * 2 + 1;

    {
        const float4* xa = (const float4*)(X + (size_t)rA * DIM);
        const float4* xb = (const float4*)(X + (size_t)rB * DIM);
        for (int c4 = lane; c4 < DIM / 4; c4 += 64) {
            const float4 a = xa[c4], b = xb[c4];
            rw[c4 * 4 + 0] = make_float2(a.x, b.x);
            rw[c4 * 4 + 1] = make_float2(a.y, b.y);
            rw[c4 * 4 + 2] = make_float2(a.z, b.z);
            rw[c4 * 4 + 3] = make_float2(a.w, b.w);
        }
        if (lane < 2) rw[DIM + lane] = make_float2(0.f, 0.f);
    }

    const int cnreg = cnts[lane < NSLOT ? lane : 0];

    for (int slot = 0; slot < NSLOT; ++slot) {
        if (slot == NW2) {      // between walks: yp = vec * yp
            const float4* v4 = (const float4*)vec;
            for (int c4 = lane; c4 < DIM / 4; c4 += 64) {
                const float4 v = v4[c4];
#pragma unroll
                for (int q = 0; q < 4; ++q) {
                    float2 tv = rw[c4 * 4 + q];
                    const float sc = (q == 0) ? v.x : (q == 1) ? v.y : (q == 2) ? v.z : v.w;
                    tv.x *= sc; tv.y *= sc;
                    rw[c4 * 4 + q] = tv;
                }
            }
        }
        const int nit = __shfl(cnreg, slot) >> 7;
        const uint4* base = recs + (size_t)slot * SLOT;

        uint4 rd0A = base[2 * 128 + lane], rd0B = base[2 * 128 + 64 + lane];
        uint4 rd1A = base[3 * 128 + lane], rd1B = base[3 * 128 + 64 + lane];
        uint4 c0A  = base[lane],           c0B  = base[64 + lane];
        uint4 c1A  = base[128 + lane],     c1B  = base[192 + lane];

        int   i0a = (int)c0A.x, j0a = (int)c0A.w;   // byte offsets
        int   i0b = (int)c0B.x, j0b = (int)c0B.w;
        float cc0a = bitf(c0A.y), ss0a = bitf(c0A.z);
        float cc0b = bitf(c0B.y), ss0b = bitf(c0B.z);
        float2 g0ai = ldrw(rw, i0a), g0aj = ldrw(rw, j0a);
        float2 g0bi = ldrw(rw, i0b), g0bj = ldrw(rw, j0b);

        int   i1a = (int)c1A.x, j1a = (int)c1A.w;
        int   i1b = (int)c1B.x, j1b = (int)c1B.w;
        float cc1a = bitf(c1A.y), ss1a = bitf(c1A.z);
        float cc1b = bitf(c1B.y), ss1b = bitf(c1B.z);
        float2 g1ai = ldrw(rw, i1a), g1aj = ldrw(rw, j1a);
        float2 g1bi = ldrw(rw, i1b), g1bj = ldrw(rw, j1b);

#pragma unroll 4
        for (int k = 0; k < nit; ++k) {
            // stage L: load records for chunk k+4 (clamped -> trailing pads)
            const int kc = (k + 4 < nit) ? (k + 4) : (nit - 1);
            const uint4 mA = base[(size_t)kc * 128 + lane];
            const uint4 mB = base[(size_t)kc * 128 + 64 + lane];

            // stage G: gather chunk k+2 (any 3 consecutive chunks disjoint)
            const int   i2a = (int)rd0A.x, j2a = (int)rd0A.w;
            const int   i2b = (int)rd0B.x, j2b = (int)rd0B.w;
            const float cc2a = bitf(rd0A.y), ss2a = bitf(rd0A.z);
            const float cc2b = bitf(rd0B.y), ss2b = bitf(rd0B.z);
            const float2 g2ai = ldrw(rw, i2a), g2aj = ldrw(rw, j2a);
            const float2 g2bi = ldrw(rw, i2b), g2bj = ldrw(rw, j2b);

            // stage C: rotate + scatter chunk k
            float2 wia, wja, wib, wjb;
            wia.x = fmaf(cc0a, g0ai.x,  ss0a * g0aj.x);
            wia.y = fmaf(cc0a, g0ai.y,  ss0a * g0aj.y);
            wja.x = fmaf(cc0a, g0aj.x, -ss0a * g0ai.x);
            wja.y = fmaf(cc0a, g0aj.y, -ss0a * g0ai.y);
            wib.x = fmaf(cc0b, g0bi.x,  ss0b * g0bj.x);
            wib.y = fmaf(cc0b, g0bi.y,  ss0b * g0bj.y);
            wjb.x = fmaf(cc0b, g0bj.x, -ss0b * g0bi.x);
            wjb.y = fmaf(cc0b, g0bj.y, -ss0b * g0bi.y);
            strw(rw, i0a, wia); strw(rw, j0a, wja);
            strw(rw, i0b, wib); strw(rw, j0b, wjb);

            i0a = i1a; j0a = j1a; cc0a = cc1a; ss0a = ss1a; g0ai = g1ai; g0aj = g1aj;
            i0b = i1b; j0b = j1b; cc0b = cc1b; ss0b = ss1b; g0bi = g1bi; g0bj = g1bj;
            i1a = i2a; j1a = j2a; cc1a = cc2a; ss1a = ss2a; g1ai = g2ai; g1aj = g2aj;
            i1b = i2b; j1b = j2b; cc1b = cc2b; ss1b = ss2b; g1bi = g2bi; g1bj = g2bj;
            rd0A = rd1A; rd0B = rd1B; rd1A = mA; rd1B = mB;
        }
    }

    float4* oa = (float4*)(out + (size_t)rA * DIM);
    float4* ob = (float4*)(out + (size_t)rB * DIM);
    const float4* qa = (const float4*)parts + (size_t)rA * (DIM / 4);
    const float4* qb = (const float4*)parts + (size_t)rB * (DIM / 4);
    for (int c4 = lane; c4 < DIM / 4; c4 += 64) {
        const float2 p0 = rw[c4 * 4 + 0], p1 = rw[c4 * 4 + 1];
        const float2 p2 = rw[c4 * 4 + 2], p3 = rw[c4 * 4 + 3];
        float4 ta = oa[c4], tb = ob[c4];
        if (nparts == 1) {
            const float4 a0 = qa[c4], b0 = qb[c4];
            ta.x += a0.x; ta.y += a0.y; ta.z += a0.z; ta.w += a0.w;
            tb.x += b0.x; tb.y += b0.y; tb.z += b0.z; tb.w += b0.w;
        }
        ta.x += p0.x; ta.y += p1.x; ta.z += p2.x; ta.w += p3.x;
        tb.x += p0.y; tb.y += p1.y; tb.z += p2.y; tb.w += p3.y;
        oa[c4] = ta; ob[c4] = tb;
    }
}

// ---------------------------------------------------------------------------
extern "C" void kernel_launch(void* const* d_in, const int* in_sizes, int n_in,
                              void* d_out, int out_size, void* d_ws, size_t ws_size,
                              hipStream_t stream) {
    const float* X    = (const float*)d_in[0];
    const float* W    = (const float*)d_in[1];
    const float* bias = (const float*)d_in[2];
    const float* vec  = (const float*)d_in[3];
    const int*   i1   = (const int*)d_in[4];
    const int*   j1   = (const int*)d_in[5];
    const float* c1   = (const float*)d_in[6];
    const float* s1   = (const float*)d_in[7];
    const int*   i2   = (const int*)d_in[8];
    const int*   j2   = (const int*)d_in[9];
    const float* c2   = (const float*)d_in[10];
    const float* s2   = (const float*)d_in[11];
    float* out = (float*)d_out;

    const size_t recs_bytes = (size_t)NSLOT * SLOT * 16;         // 6.29 MiB
    const size_t off_parts  = recs_bytes + 4096;
    const size_t off_wb     = off_parts + (size_t)ROWS * DIM * 4;    // +8 MiB
    const size_t off_xb     = off_wb + (size_t)DIM * DIM * 2;        // +32 MiB
    const size_t need       = off_xb + (size_t)ROWS * DIM * 2;       // +4 MiB

    uint4* recs  = (uint4*)d_ws;
    int*   cnts  = (int*)((char*)d_ws + recs_bytes);
    float* parts = (float*)((char*)d_ws + off_parts);
    short* wbuf  = (short*)((char*)d_ws + off_wb);
    short* xbuf  = (short*)((char*)d_ws + off_xb);
    const bool bf = (ws_size >= need);

    hipLaunchKernelGGL(kfused, dim3(NSLOT + (bf ? (NCVW + NCVX) : 0)), dim3(KT), 0, stream,
                       i1, j1, c1, s1, i2, j2, c2, s2, recs, cnts,
                       bf ? 1 : 0, W, X, wbuf, xbuf);
    if (bf)
        hipLaunchKernelGGL(kgemm_bf, dim3(256), dim3(256), 0, stream, xbuf, wbuf, bias, out, parts);
    else
        hipLaunchKernelGGL(kgemm_small, dim3(256), dim3(256), 0, stream, X, W, bias, out);
    hipLaunchKernelGGL(kwalk, dim3(ROWS / 2), dim3(64), 0, stream,
                       X, vec, recs, cnts, parts, bf ? 1 : 0, out);
}

// Round 10
// 279.708 us; speedup vs baseline: 1.5312x; 1.4296x over previous
//
#include <hip/hip_runtime.h>

// KacLayer: out[512][4096] = x @ W^T + b  +  Kac2( vec * Kac1( x ) )
//
//  kfused: blocks 0..11: per-8192-step window scheduler.
//          Election (round-stamped atomicMin keys, 2 barriers/round) assigns
//          each step its dependency DEPTH; same-level steps are column-
//          disjoint and depth strictly increases along same-column chains.
//          One-shot LEVEL LAYOUT: level r -> ceil(cnt_r/128) chunks at
//          base_r, +2 gap chunks between occupied levels => column-sharing
//          steps >=3 chunks apart (any 3 consecutive chunks disjoint).
//          Records scattered straight to global (region prefilled with
//          identity pads). Bit-exact reorder of commuting Givens rotations.
//          blocks 12..1163: fp32->bf16 convert of W and X into d_ws.
//  kgemm_bf: bf16 MFMA GEMM from pre-converted W/X, 128x128 tile, BK=128,
//          XOR-swizzled LDS, Ksplit=2 (partial buffer in d_ws).
//  kwalk : 1 wave / 2 rows (float2-interleaved LDS), 3-stage pipeline
//          (records loaded +4, gathered +2, scattered at 0); epilogue adds
//          split-K partial + walked rows into out.

#define DIM    4096
#define ROWS   512
#define NSTEPS 49152
#define WSTEPS 8192
#define NW2    (NSTEPS / WSTEPS)   // 6 windows per walk
#define NSLOT  (2 * NW2)           // 12 slots
#define MAXCHP 256
#define NSG    16                  // rank subgroups (one per wave)
#define CHUNK  128
#define SLOT   (MAXCHP * CHUNK)    // 32768 records per slot
#define MAXR   96
#define PADI   4096
#define PADJ   4097
#define KT     1024                // scheduler threads
#define SPT    (WSTEPS / KT)       // 8 steps per thread
#define NCVW   1024                // W-convert blocks
#define NCVX   128                 // X-convert blocks

typedef short  short8 __attribute__((ext_vector_type(8)));
typedef __bf16 bf16x8 __attribute__((ext_vector_type(8)));
typedef float  f32x4  __attribute__((ext_vector_type(4)));

__device__ inline short f2bf(float f) {
    unsigned u = __builtin_bit_cast(unsigned, f);
    u += 0x7FFFu + ((u >> 16) & 1u);
    return (short)(u >> 16);
}
__device__ inline short8 pack8(float4 a, float4 b) {
    short8 r;
    r[0] = f2bf(a.x); r[1] = f2bf(a.y); r[2] = f2bf(a.z); r[3] = f2bf(a.w);
    r[4] = f2bf(b.x); r[5] = f2bf(b.y); r[6] = f2bf(b.z); r[7] = f2bf(b.w);
    return r;
}
__device__ inline float bitf(unsigned u) { return __builtin_bit_cast(float, u); }
__device__ inline float2 ldrw(const float2* rw, int boff) {
    return *(const float2*)((const char*)rw + boff);
}
__device__ inline void strw(float2* rw, int boff, float2 v) {
    *(float2*)((char*)rw + boff) = v;
}

// ---------------------------------------------------------------------------
// 1) fused scheduler (blocks 0..NSLOT-1) + bf16 convert (blocks NSLOT..)
// ---------------------------------------------------------------------------
__global__ __launch_bounds__(KT) void kfused(
    const int* __restrict__ i1, const int* __restrict__ j1,
    const float* __restrict__ c1, const float* __restrict__ s1,
    const int* __restrict__ i2, const int* __restrict__ j2,
    const float* __restrict__ c2, const float* __restrict__ s2,
    uint4* __restrict__ recs, int* __restrict__ cnts,
    int doconv, const float* __restrict__ W, const float* __restrict__ X,
    short* __restrict__ wb, short* __restrict__ xb) {

    // ---------------- convert path ----------------
    if (blockIdx.x >= NSLOT) {
        if (!doconv) return;
        const int cb = blockIdx.x - NSLOT;
        const float* src; short* dst; size_t base;
        if (cb < NCVW) { src = W; dst = wb; base = (size_t)cb * 16384; }
        else           { src = X; dst = xb; base = (size_t)(cb - NCVW) * 16384; }
        const size_t o = base + (size_t)threadIdx.x * 16;
        const float4* s4 = (const float4*)(src + o);
        const float4 a0 = s4[0], a1 = s4[1], a2 = s4[2], a3 = s4[3];
        *(short8*)(dst + o)     = pack8(a0, a1);
        *(short8*)(dst + o + 8) = pack8(a2, a3);
        return;
    }

    // ---------------- scheduler path ----------------
    __shared__ unsigned tbl[DIM];          // election keys      (16 KB)
    __shared__ unsigned spair[WSTEPS];     // li | lj<<16        (32 KB)
    __shared__ unsigned lvrk[WSTEPS];      // rank<<8 | level    (32 KB)
    __shared__ int lcnt[MAXR * NSG];       // per-(level,wave) counters (6 KB)
    __shared__ int ltot[MAXR], chbase[MAXR];
    __shared__ int nchunks;

    const int b    = blockIdx.x;           // 0..11
    const int walk = b / NW2;
    const int w    = b % NW2;
    const int t    = threadIdx.x;
    const int gb   = w * WSTEPS;
    const int sg   = t >> 6;               // wave id 0..15

    const int*   I = walk ? i2 : i1;
    const int*   J = walk ? j2 : j1;
    const float* C = walk ? c2 : c1;
    const float* S = walk ? s2 : s1;

    uint4* slotp = recs + (size_t)b * SLOT;

    // prefill slot region with identity-pad records (coalesced)
    {
        const uint4 padrec = { (unsigned)(PADI * 8), 0x3F800000u, 0u, (unsigned)(PADJ * 8) };
        for (int k = t; k < SLOT; k += KT) slotp[k] = padrec;
    }
    for (int s = t; s < WSTEPS; s += KT)
        spair[s] = (unsigned)I[gb + s] | ((unsigned)J[gb + s] << 16);
    for (int k = t; k < DIM; k += KT) tbl[k] = 0xFFFFFFFFu;
    for (int k = t; k < MAXR * NSG; k += KT) lcnt[k] = 0;
    __syncthreads();

    // ---- election: 2 barriers/round; level = DAG depth --------------------
    unsigned pmask = (1u << SPT) - 1u;
    for (int rr = 0; rr < MAXR; ++rr) {
        const unsigned rk = (unsigned)(MAXR - 1 - rr) << 13;
#pragma unroll
        for (int q = 0; q < SPT; ++q)
            if (pmask & (1u << q)) {
                const int s = q * KT + t;
                const unsigned sp = spair[s];
                const unsigned key = rk | (unsigned)s;
                atomicMin(&tbl[sp & 0xFFFFu], key);
                atomicMin(&tbl[sp >> 16], key);
            }
        __syncthreads();                                   // B1
#pragma unroll
        for (int q = 0; q < SPT; ++q)
            if (pmask & (1u << q)) {
                const int s = q * KT + t;
                const unsigned sp = spair[s];
                const unsigned key = rk | (unsigned)s;
                if (tbl[sp & 0xFFFFu] == key && tbl[sp >> 16] == key) {
                    const int rank = atomicAdd(&lcnt[rr * NSG + sg], 1);
                    lvrk[s] = ((unsigned)rank << 8) | (unsigned)rr;
                    pmask &= ~(1u << q);
                }
            }
        const int np = __syncthreads_count(pmask != 0);    // B2
        if (np == 0) break;
    }
    // safety net (statistically unreachable): dump leftovers into last level
#pragma unroll
    for (int q = 0; q < SPT; ++q)
        if (pmask & (1u << q)) {
            const int s = q * KT + t;
            const int rank = atomicAdd(&lcnt[(MAXR - 1) * NSG + sg], 1);
            lvrk[s] = ((unsigned)rank << 8) | (unsigned)(MAXR - 1);
        }
    __syncthreads();

    // ---- one-shot layout --------------------------------------------------
    // per-level subgroup exclusive prefix (thread r handles level r)
    if (t < MAXR) {
        int run = 0;
        for (int g = 0; g < NSG; ++g) {
            const int v = lcnt[t * NSG + g];
            lcnt[t * NSG + g] = run;
            run += v;
        }
        ltot[t] = run;
    }
    __syncthreads();
    // chunk bases: w_r = ceil(tot/128)+2 for non-empty levels; wave scan
    if (t < 64) {
        const int l = t;
        const int tot1 = ltot[l];
        const int w1 = (tot1 > 0) ? (((tot1 + 127) >> 7) + 2) : 0;
        int x1 = w1;
        for (int off = 1; off < 64; off <<= 1) {
            const int v = __shfl_up(x1, off);
            if (l >= off) x1 += v;
        }
        chbase[l] = x1 - w1;
        const int seg1 = __shfl(x1, 63);
        const int l2 = 64 + (l & 31);
        const int tot2 = ltot[l2];
        const int w2 = (tot2 > 0) ? (((tot2 + 127) >> 7) + 2) : 0;
        int x2 = w2;
        for (int off = 1; off < 32; off <<= 1) {
            const int v = __shfl_up(x2, off);
            if ((l & 31) >= off) x2 += v;
        }
        if (l < 32) chbase[l2] = seg1 + x2 - w2;
        if (l == 31) nchunks = seg1 + x2;
    }
    __syncthreads();
    if (t == 0) {
        int nc = nchunks;
        if (nc < 4) nc = 4;
        if (nc > MAXCHP) nc = MAXCHP;
        cnts[b] = nc * CHUNK;
    }

    // ---- record emission (coalesced C/S reads, scattered 16B stores) ------
#pragma unroll
    for (int q = 0; q < SPT; ++q) {
        const int s = q * KT + t;
        const unsigned v = lvrk[s];
        const int lvl  = (int)(v & 0xFFu);
        const int rank = (int)(v >> 8) + lcnt[lvl * NSG + sg];
        const int p    = (chbase[lvl] + (rank >> 7)) * CHUNK + (rank & 127);
        if (p < SLOT) {
            const unsigned sp = spair[s];
            const int g = gb + s;
            uint4 r;
            r.x = (sp & 0xFFFFu) * 8u;
            r.y = __builtin_bit_cast(unsigned, C[g]);
            r.z = __builtin_bit_cast(unsigned, S[g]);
            r.w = (sp >> 16) * 8u;
            slotp[p] = r;
        }
    }
}

// ---------------------------------------------------------------------------
// 2a) bf16 GEMM from pre-converted inputs: 128x128 tile, BK=128, Ksplit=2
// ---------------------------------------------------------------------------
__global__ __launch_bounds__(256) void kgemm_bf(const short* __restrict__ Xb, const short* __restrict__ Wb,
                                                const float* __restrict__ bias, float* __restrict__ out,
                                                float* __restrict__ parts) {
    __shared__ short As[128 * 128];
    __shared__ short Bs[128 * 128];
    const int bid  = blockIdx.x;
    const int ks   = bid & 1;
    const int tile = bid >> 1;                 // 0..127
    const int bm   = (tile >> 5) * 128;
    const int bn   = (tile & 31) * 128;
    const int tid  = threadIdx.x;
    const int lane = tid & 63;
    const int wv   = tid >> 6;
    const int wr   = (wv >> 1) * 64;
    const int wc   = (wv & 1) * 64;
    const int fr   = lane & 15;
    const int ke   = (lane >> 4) * 8;

    f32x4 acc[4][4];
#pragma unroll
    for (int m = 0; m < 4; ++m)
#pragma unroll
        for (int n = 0; n < 4; ++n) acc[m][n] = (f32x4){0.f, 0.f, 0.f, 0.f};

    const int tr2 = tid >> 1;                  // staging row 0..127
    const int hh  = tid & 1;                   // 64-elem half
    const int wm  = tr2 & 7;                   // swizzle mask
    const short* gxa = Xb + (size_t)(bm + tr2) * DIM + hh * 64;
    const short* gwb = Wb + (size_t)(bn + tr2) * DIM + hh * 64;

    for (int kt = 0; kt < 16; ++kt) {
        const int k0 = ks * 2048 + kt * 128;
        short8 ar[8], br[8];
#pragma unroll
        for (int q = 0; q < 8; ++q) ar[q] = *(const short8*)(gxa + k0 + q * 8);
#pragma unroll
        for (int q = 0; q < 8; ++q) br[q] = *(const short8*)(gwb + k0 + q * 8);
        __syncthreads();                       // previous tile's reads done
#pragma unroll
        for (int q = 0; q < 8; ++q) {
            const int sl = (hh * 8 + q) ^ wm;  // XOR-swizzled 16B slot
            *(short8*)&As[tr2 * 128 + sl * 8] = ar[q];
            *(short8*)&Bs[tr2 * 128 + sl * 8] = br[q];
        }
        __syncthreads();
#pragma unroll
        for (int kk = 0; kk < 128; kk += 32) {
            const int sbase = (kk + ke) >> 3;
            short8 af[4], bf[4];
#pragma unroll
            for (int m = 0; m < 4; ++m) {
                const int R = wr + m * 16 + fr;
                af[m] = *(const short8*)&As[R * 128 + ((sbase ^ (R & 7)) << 3)];
            }
#pragma unroll
            for (int n = 0; n < 4; ++n) {
                const int R = wc + n * 16 + fr;
                bf[n] = *(const short8*)&Bs[R * 128 + ((sbase ^ (R & 7)) << 3)];
            }
#pragma unroll
            for (int m = 0; m < 4; ++m)
#pragma unroll
                for (int n = 0; n < 4; ++n)
                    acc[m][n] = __builtin_amdgcn_mfma_f32_16x16x32_bf16(
                        __builtin_bit_cast(bf16x8, af[m]),
                        __builtin_bit_cast(bf16x8, bf[n]),
                        acc[m][n], 0, 0, 0);
        }
    }
    float* dst = ks ? parts : out;
#pragma unroll
    for (int n = 0; n < 4; ++n) {
        const int col = bn + wc + n * 16 + fr;
        const float bv = ks ? 0.f : bias[col];
#pragma unroll
        for (int m = 0; m < 4; ++m) {
            const int rbase = bm + wr + m * 16 + (lane >> 4) * 4;
#pragma unroll
            for (int r = 0; r < 4; ++r)
                dst[(size_t)(rbase + r) * DIM + col] = acc[m][n][r] + bv;
        }
    }
}

// ---------------------------------------------------------------------------
// 2b) fallback GEMM: fp32 staging, BM=64 BN=128, full K, 256 thr
// ---------------------------------------------------------------------------
#define LDT 72
__global__ __launch_bounds__(256) void kgemm_small(const float* __restrict__ X, const float* __restrict__ W,
                                                   const float* __restrict__ bias, float* __restrict__ out) {
    __shared__ short As[64 * LDT];
    __shared__ short Bs[128 * LDT];
    const int tid  = threadIdx.x;
    const int bn   = (blockIdx.x & 31) * 128;
    const int bm   = (blockIdx.x >> 5) * 64;
    const int lane = tid & 63;
    const int wv   = tid >> 6;
    const int wr   = (wv >> 1) * 32;
    const int wc   = (wv & 1) * 64;
    const int fr   = lane & 15;
    const int ke   = (lane >> 4) * 8;

    f32x4 acc[2][4];
#pragma unroll
    for (int m = 0; m < 2; ++m)
#pragma unroll
        for (int n = 0; n < 4; ++n) acc[m][n] = (f32x4){0.f, 0.f, 0.f, 0.f};

    const int tr = tid >> 2;
    const int tc = (tid & 3) << 4;

    for (int kt = 0; kt < DIM / 64; ++kt) {
        const int k0 = kt * 64;
        float4 ra[4], rb[2][4];
        {
            const float4* ga = (const float4*)(X + (size_t)(bm + tr) * DIM + k0 + tc);
#pragma unroll
            for (int q = 0; q < 4; ++q) ra[q] = ga[q];
#pragma unroll
            for (int h = 0; h < 2; ++h) {
                const float4* gw = (const float4*)(W + (size_t)(bn + h * 64 + tr) * DIM + k0 + tc);
#pragma unroll
                for (int q = 0; q < 4; ++q) rb[h][q] = gw[q];
            }
        }
        __syncthreads();
        *(short8*)&As[tr * LDT + tc]     = pack8(ra[0], ra[1]);
        *(short8*)&As[tr * LDT + tc + 8] = pack8(ra[2], ra[3]);
#pragma unroll
        for (int h = 0; h < 2; ++h) {
            *(short8*)&Bs[(h * 64 + tr) * LDT + tc]     = pack8(rb[h][0], rb[h][1]);
            *(short8*)&Bs[(h * 64 + tr) * LDT + tc + 8] = pack8(rb[h][2], rb[h][3]);
        }
        __syncthreads();
#pragma unroll
        for (int kk = 0; kk < 64; kk += 32) {
            short8 af[2], bf[4];
#pragma unroll
            for (int m = 0; m < 2; ++m)
                af[m] = *(const short8*)&As[(wr + m * 16 + fr) * LDT + kk + ke];
#pragma unroll
            for (int n = 0; n < 4; ++n)
                bf[n] = *(const short8*)&Bs[(wc + n * 16 + fr) * LDT + kk + ke];
#pragma unroll
            for (int m = 0; m < 2; ++m)
#pragma unroll
                for (int n = 0; n < 4; ++n)
                    acc[m][n] = __builtin_amdgcn_mfma_f32_16x16x32_bf16(
                        __builtin_bit_cast(bf16x8, af[m]),
                        __builtin_bit_cast(bf16x8, bf[n]),
                        acc[m][n], 0, 0, 0);
        }
    }
#pragma unroll
    for (int n = 0; n < 4; ++n) {
        const int col = bn + wc + n * 16 + fr;
        const float bv = bias[col];
#pragma unroll
        for (int m = 0; m < 2; ++m) {
            const int rbase = bm + wr + m * 16 + (lane >> 4) * 4;
#pragma unroll
            for (int r = 0; r < 4; ++r)
                out[(size_t)(rbase + r) * DIM + col] = acc[m][n][r] + bv;
        }
    }
}

// ---------------------------------------------------------------------------
// 3) walk kernel: 1 wave / 2 rows, 3-stage pipeline; adds split-K partial
// ---------------------------------------------------------------------------
__global__ __launch_bounds__(64) void kwalk(const float* __restrict__ X, const float* __restrict__ vec,
                                            const uint4* __restrict__ recs, const int* __restrict__ cnts,
                                            const float* __restrict__ parts, int nparts,
                                            float* __restrict__ out) {
    __shared__ float2 rw[DIM + 2];
    const int pr   = blockIdx.x;
    const int lane = threadIdx.x;
    const int rA   = pr * 2, rB = pr * 2 + 1;

    {
        const float4* xa = (const float4*)(X + (size_t)rA * DIM);
        const float4* xb = (const float4*)(X + (size_t)rB * DIM);
        for (int c4 = lane; c4 < DIM / 4; c4 += 64) {
            const float4 a = xa[c4], b = xb[c4];
            rw[c4 * 4 + 0] = make_float2(a.x, b.x);
            rw[c4 * 4 + 1] = make_float2(a.y, b.y);
            rw[c4 * 4 + 2] = make_float2(a.z, b.z);
            rw[c4 * 4 + 3] = make_float2(a.w, b.w);
        }
        if (lane < 2) rw[DIM + lane] = make_float2(0.f, 0.f);
    }

    const int cnreg = cnts[lane < NSLOT ? lane : 0];

    for (int slot = 0; slot < NSLOT; ++slot) {
        if (slot == NW2) {      // between walks: yp = vec * yp
            const float4* v4 = (const float4*)vec;
            for (int c4 = lane; c4 < DIM / 4; c4 += 64) {
                const float4 v = v4[c4];
#pragma unroll
                for (int q = 0; q < 4; ++q) {
                    float2 tv = rw[c4 * 4 + q];
                    const float sc = (q == 0) ? v.x : (q == 1) ? v.y : (q == 2) ? v.z : v.w;
                    tv.x *= sc; tv.y *= sc;
                    rw[c4 * 4 + q] = tv;
                }
            }
        }
        const int nit = __shfl(cnreg, slot) >> 7;
        const uint4* base = recs + (size_t)slot * SLOT;

        uint4 rd0A = base[2 * 128 + lane], rd0B = base[2 * 128 + 64 + lane];
        uint4 rd1A = base[3 * 128 + lane], rd1B = base[3 * 128 + 64 + lane];
        uint4 c0A  = base[lane],           c0B  = base[64 + lane];
        uint4 c1A  = base[128 + lane],     c1B  = base[192 + lane];

        int   i0a = (int)c0A.x, j0a = (int)c0A.w;   // byte offsets
        int   i0b = (int)c0B.x, j0b = (int)c0B.w;
        float cc0a = bitf(c0A.y), ss0a = bitf(c0A.z);
        float cc0b = bitf(c0B.y), ss0b = bitf(c0B.z);
        float2 g0ai = ldrw(rw, i0a), g0aj = ldrw(rw, j0a);
        float2 g0bi = ldrw(rw, i0b), g0bj = ldrw(rw, j0b);

        int   i1a = (int)c1A.x, j1a = (int)c1A.w;
        int   i1b = (int)c1B.x, j1b = (int)c1B.w;
        float cc1a = bitf(c1A.y), ss1a = bitf(c1A.z);
        float cc1b = bitf(c1B.y), ss1b = bitf(c1B.z);
        float2 g1ai = ldrw(rw, i1a), g1aj = ldrw(rw, j1a);
        float2 g1bi = ldrw(rw, i1b), g1bj = ldrw(rw, j1b);

#pragma unroll 4
        for (int k = 0; k < nit; ++k) {
            // stage L: load records for chunk k+4 (clamped -> trailing pads)
            const int kc = (k + 4 < nit) ? (k + 4) : (nit - 1);
            const uint4 mA = base[(size_t)kc * 128 + lane];
            const uint4 mB = base[(size_t)kc * 128 + 64 + lane];

            // stage G: gather chunk k+2 (any 3 consecutive chunks disjoint)
            const int   i2a = (int)rd0A.x, j2a = (int)rd0A.w;
            const int   i2b = (int)rd0B.x, j2b = (int)rd0B.w;
            const float cc2a = bitf(rd0A.y), ss2a = bitf(rd0A.z);
            const float cc2b = bitf(rd0B.y), ss2b = bitf(rd0B.z);
            const float2 g2ai = ldrw(rw, i2a), g2aj = ldrw(rw, j2a);
            const float2 g2bi = ldrw(rw, i2b), g2bj = ldrw(rw, j2b);

            // stage C: rotate + scatter chunk k
            float2 wia, wja, wib, wjb;
            wia.x = fmaf(cc0a, g0ai.x,  ss0a * g0aj.x);
            wia.y = fmaf(cc0a, g0ai.y,  ss0a * g0aj.y);
            wja.x = fmaf(cc0a, g0aj.x, -ss0a * g0ai.x);
            wja.y = fmaf(cc0a, g0aj.y, -ss0a * g0ai.y);
            wib.x = fmaf(cc0b, g0bi.x,  ss0b * g0bj.x);
            wib.y = fmaf(cc0b, g0bi.y,  ss0b * g0bj.y);
            wjb.x = fmaf(cc0b, g0bj.x, -ss0b * g0bi.x);
            wjb.y = fmaf(cc0b, g0bj.y, -ss0b * g0bi.y);
            strw(rw, i0a, wia); strw(rw, j0a, wja);
            strw(rw, i0b, wib); strw(rw, j0b, wjb);

            i0a = i1a; j0a = j1a; cc0a = cc1a; ss0a = ss1a; g0ai = g1ai; g0aj = g1aj;
            i0b = i1b; j0b = j1b; cc0b = cc1b; ss0b = ss1b; g0bi = g1bi; g0bj = g1bj;
            i1a = i2a; j1a = j2a; cc1a = cc2a; ss1a = ss2a; g1ai = g2ai; g1aj = g2aj;
            i1b = i2b; j1b = j2b; cc1b = cc2b; ss1b = ss2b; g1bi = g2bi; g1bj = g2bj;
            rd0A = rd1A; rd0B = rd1B; rd1A = mA; rd1B = mB;
        }
    }

    float4* oa = (float4*)(out + (size_t)rA * DIM);
    float4* ob = (float4*)(out + (size_t)rB * DIM);
    const float4* qa = (const float4*)parts + (size_t)rA * (DIM / 4);
    const float4* qb = (const float4*)parts + (size_t)rB * (DIM / 4);
    for (int c4 = lane; c4 < DIM / 4; c4 += 64) {
        const float2 p0 = rw[c4 * 4 + 0], p1 = rw[c4 * 4 + 1];
        const float2 p2 = rw[c4 * 4 + 2], p3 = rw[c4 * 4 + 3];
        float4 ta = oa[c4], tb = ob[c4];
        if (nparts == 1) {
            const float4 a0 = qa[c4], b0 = qb[c4];
            ta.x += a0.x; ta.y += a0.y; ta.z += a0.z; ta.w += a0.w;
            tb.x += b0.x; tb.y += b0.y; tb.z += b0.z; tb.w += b0.w;
        }
        ta.x += p0.x; ta.y += p1.x; ta.z += p2.x; ta.w += p3.x;
        tb.x += p0.y; tb.y += p1.y; tb.z += p2.y; tb.w += p3.y;
        oa[c4] = ta; ob[c4] = tb;
    }
}

// ---------------------------------------------------------------------------
extern "C" void kernel_launch(void* const* d_in, const int* in_sizes, int n_in,
                              void* d_out, int out_size, void* d_ws, size_t ws_size,
                              hipStream_t stream) {
    const float* X    = (const float*)d_in[0];
    const float* W    = (const float*)d_in[1];
    const float* bias = (const float*)d_in[2];
    const float* vec  = (const float*)d_in[3];
    const int*   i1   = (const int*)d_in[4];
    const int*   j1   = (const int*)d_in[5];
    const float* c1   = (const float*)d_in[6];
    const float* s1   = (const float*)d_in[7];
    const int*   i2   = (const int*)d_in[8];
    const int*   j2   = (const int*)d_in[9];
    const float* c2   = (const float*)d_in[10];
    const float* s2   = (const float*)d_in[11];
    float* out = (float*)d_out;

    const size_t recs_bytes = (size_t)NSLOT * SLOT * 16;         // 6.29 MiB
    const size_t off_parts  = recs_bytes + 4096;
    const size_t off_wb     = off_parts + (size_t)ROWS * DIM * 4;    // +8 MiB
    const size_t off_xb     = off_wb + (size_t)DIM * DIM * 2;        // +32 MiB
    const size_t need       = off_xb + (size_t)ROWS * DIM * 2;       // +4 MiB

    uint4* recs  = (uint4*)d_ws;
    int*   cnts  = (int*)((char*)d_ws + recs_bytes);
    float* parts = (float*)((char*)d_ws + off_parts);
    short* wbuf  = (short*)((char*)d_ws + off_wb);
    short* xbuf  = (short*)((char*)d_ws + off_xb);
    const bool bf = (ws_size >= need);

    hipLaunchKernelGGL(kfused, dim3(NSLOT + (bf ? (NCVW + NCVX) : 0)), dim3(KT), 0, stream,
                       i1, j1, c1, s1, i2, j2, c2, s2, recs, cnts,
                       bf ? 1 : 0, W, X, wbuf, xbuf);
    if (bf)
        hipLaunchKernelGGL(kgemm_bf, dim3(256), dim3(256), 0, stream, xbuf, wbuf, bias, out, parts);
    else
        hipLaunchKernelGGL(kgemm_small, dim3(256), dim3(256), 0, stream, X, W, bias, out);
    hipLaunchKernelGGL(kwalk, dim3(ROWS / 2), dim3(64), 0, stream,
                       X, vec, recs, cnts, parts, bf ? 1 : 0, out);
}